// Round 16
// baseline (363.734 us; speedup 1.0000x reference)
//
#include <hip/hip_runtime.h>
#include <cstdint>
#include <cstddef>

// Problem constants (fixed by setup_inputs)
#define BB 4
#define NN 8192
#define MM 4096
#define CC 64
#define SS 32
#define CH 67      // 3 (xyz) + 64 (features)
#define NC 512     // 8x8x8 grid cells per batch
#define RMARG 0.1201f   // conservative cell-range radius (> sqrt(kRR) + fp slop)

typedef float f32x4 __attribute__((ext_vector_type(4)));   // nt-store-able 16B
typedef unsigned short u16;

// radius^2 exactly as Python computes it: double 0.12*0.12 rounded once to f32.
__device__ __constant__ float kRR = (float)(0.12 * 0.12);

__device__ __forceinline__ int cell_of(float x, float y, float z) {
    const int ix = min((int)(x * 8.0f), 7);
    const int iy = min((int)(y * 8.0f), 7);
    const int iz = min((int)(z * 8.0f), 7);
    return (ix << 6) + (iy << 3) + iz;   // z contiguous within (ix,iy) row
}

// inclusive scan over 512 values (tid 0..511, 8 waves); wsum = LDS int[16].
__device__ __forceinline__ int block_scan512(int v, int tid, int* wsum) {
    int incl = v;
    #pragma unroll
    for (int d = 1; d < 64; d <<= 1) {
        const int t = __shfl_up(incl, d);
        if ((tid & 63) >= d) incl += t;
    }
    if ((tid & 63) == 63 && tid < NC) wsum[tid >> 6] = incl;
    __syncthreads();
    if (tid < 8) {
        const int ws = wsum[tid];
        int w2 = ws;
        #pragma unroll
        for (int d = 1; d < 8; d <<= 1) {
            const int t = __shfl_up(w2, d);
            if (tid >= d) w2 += t;
        }
        wsum[tid] = w2 - ws;   // exclusive wave-offset
    }
    __syncthreads();
    return incl + wsum[(tid >> 6) & 7];
}

// ---- k_prep: grid build + xyz SoA, 4 blocks x 1024 (build part verified) ---
__global__ __launch_bounds__(1024) void k_prep(
    const float* __restrict__ xyz,      // (B,N,3)
    float* __restrict__ xt,             // (B,3,N) out plain SoA
    int* __restrict__ cellStart,        // (B,513) out
    float4* __restrict__ pk)            // (B,N) out packed cell-ordered
{
    __shared__ int sm[NC];
    __shared__ int cur[NC];
    __shared__ int wsum[16];
    const int b = (int)blockIdx.x;
    const int tid = (int)threadIdx.x;

    if (tid < NC) sm[tid] = 0;
    __syncthreads();

    float xs[8], ys[8], zs[8];
    int cl[8];
    const float* __restrict__ xb = xyz + (size_t)b * NN * 3;
    float* __restrict__ xtb = xt + (size_t)b * 3 * NN;
    #pragma unroll
    for (int k = 0; k < 8; ++k) {
        const int n = (k << 10) + tid;
        xs[k] = xb[n * 3 + 0];
        ys[k] = xb[n * 3 + 1];
        zs[k] = xb[n * 3 + 2];
        cl[k] = cell_of(xs[k], ys[k], zs[k]);
        atomicAdd(&sm[cl[k]], 1);
        xtb[0 * NN + n] = xs[k];        // coalesced SoA writes
        xtb[1 * NN + n] = ys[k];
        xtb[2 * NN + n] = zs[k];
    }
    __syncthreads();

    const int v = (tid < NC) ? sm[tid] : 0;
    const int incl = block_scan512(v, tid, wsum);
    if (tid < NC) {
        cellStart[b * (NC + 1) + tid + 1] = incl;
        cur[tid] = incl - v;                   // exclusive prefix
        if (tid == 0) cellStart[b * (NC + 1)] = 0;
    }
    __syncthreads();

    #pragma unroll
    for (int k = 0; k < 8; ++k) {
        const int n = (k << 10) + tid;
        const int pos = atomicAdd(&cur[cl[k]], 1);
        pk[b * NN + pos] = make_float4(xs[k], ys[k], zs[k], __int_as_float(n));
    }
}

// ---- k_ballq: bitmap ball-query (verified R12 scan/extract); writes u16 idx
__global__ __launch_bounds__(256) void k_ballq(
    const float4* __restrict__ pk,      // (B,N) packed cell-ordered (x,y,z,idx)
    const int* __restrict__ cellStart,  // (B,513)
    const float* __restrict__ new_xyz,  // (B,M,3)
    u16* __restrict__ idx)              // (B,M,32) out
{
    __shared__ unsigned int bm[4][2][NN / 32];   // 1 KiB bitmap per query
    __shared__ int slots_sm[4][2][SS];

    const int tid = (int)threadIdx.x;
    const int lane = tid & 63;
    const int w = tid >> 6;
    const int pair = (int)blockIdx.x * 4 + w;    // 0 .. BB*MM/2-1
    const int b = pair >> 11;                    // / (MM/2)
    const int m0 = (pair & 2047) << 1;           // even query index

    #pragma unroll
    for (int k = 0; k < 8; ++k) bm[w][k & 1][((k >> 1) << 6) + lane] = 0u;

    const float* __restrict__ qb = new_xyz + ((size_t)b * MM + m0) * 3;
    const float cxq[2] = { qb[0], qb[3] };
    const float cyq[2] = { qb[1], qb[4] };
    const float czq[2] = { qb[2], qb[5] };
    const float rr = kRR;

    const int* __restrict__ cs = cellStart + b * (NC + 1);
    const float4* __restrict__ pb = pk + b * NN;

    int Kcq[2];

    #pragma unroll
    for (int q = 0; q < 2; ++q) {               // compile-time unrolled
        const float cx = cxq[q], cy = cyq[q], cz = czq[q];
        unsigned int* __restrict__ bitmap = bm[w][q];
        int* __restrict__ slot = slots_sm[w][q];

        const int x0 = max(0, (int)((cx - RMARG) * 8.0f));
        const int x1 = min(7, (int)((cx + RMARG) * 8.0f));
        const int y0 = max(0, (int)((cy - RMARG) * 8.0f));
        const int y1 = min(7, (int)((cy + RMARG) * 8.0f));
        const int z0 = max(0, (int)((cz - RMARG) * 8.0f));
        const int z1 = min(7, (int)((cz + RMARG) * 8.0f));

        // prefetch all pair bounds lane-parallel (npair <= 9)
        const int ny = y1 - y0 + 1;
        const int npair = (x1 - x0 + 1) * ny;
        int begL = 0, endL = 0;
        if (lane < npair) {
            const int px = lane / ny;
            const int py = lane - px * ny;
            const int cb2 = ((x0 + px) << 6) + ((y0 + py) << 3);
            begL = cs[cb2 + z0];
            endL = cs[cb2 + z1 + 1];
        }

        for (int p = 0; p < npair; ++p) {
            const int beg = __shfl(begL, p);
            const int end = __shfl(endL, p);
            for (int off = beg; off < end; off += 64) {
                const int a = off + lane;
                const bool act = a < end;
                const float4 v = pb[act ? a : beg];   // coalesced 16B/lane
                const float dx = __fsub_rn(v.x, cx);
                const float dy = __fsub_rn(v.y, cy);
                const float dz = __fsub_rn(v.z, cz);
                const float d2 = __fadd_rn(__fadd_rn(__fmul_rn(dx, dx), __fmul_rn(dy, dy)),
                                           __fmul_rn(dz, dz));
                if (act && d2 < rr) {
                    const int n = __float_as_int(v.w);
                    atomicOr(&bitmap[n >> 5], 1u << (n & 31));
                }
            }
        }

        // extract first SS set bits, ascending (verified R9..R15)
        const uint4 wv = *reinterpret_cast<const uint4*>(&bitmap[lane << 2]);
        const int pc = __popc(wv.x) + __popc(wv.y) + __popc(wv.z) + __popc(wv.w);
        int incl = pc;
        #pragma unroll
        for (int d = 1; d < 64; d <<= 1) {
            const int t = __shfl_up(incl, d);
            if (lane >= d) incl += t;
        }
        const int K = __shfl(incl, 63);
        int r = incl - pc;
        if (r < SS) {
            const int base = lane << 7;
            unsigned int mw0 = wv.x, mw1 = wv.y, mw2 = wv.z, mw3 = wv.w;
            while (mw0 && r < SS) { slot[r++] = base +  0 + __builtin_ctz(mw0); mw0 &= mw0 - 1; }
            while (mw1 && r < SS) { slot[r++] = base + 32 + __builtin_ctz(mw1); mw1 &= mw1 - 1; }
            while (mw2 && r < SS) { slot[r++] = base + 64 + __builtin_ctz(mw2); mw2 &= mw2 - 1; }
            while (mw3 && r < SS) { slot[r++] = base + 96 + __builtin_ctz(mw3); mw3 &= mw3 - 1; }
        }
        Kcq[q] = (K < SS) ? K : SS;
    }
    // same-wave LDS write->read is in-order; no barrier needed.

    const int q = lane >> 5;
    const int s = lane & 31;
    const int Kc = q ? Kcq[1] : Kcq[0];
    int n_of;
    if (Kc == 0) n_of = 0;                      // no hits: reference yields idx 0
    else n_of = slots_sm[w][q][(s < Kc) ? s : 0];

    // wave writes 64 u16 = 128 B contiguous (slots of m0 then m0+1)
    u16* dst = idx + ((size_t)b * MM + m0) * SS;
    dst[lane] = (u16)n_of;
}

// ---- k_gather: block = (b, channel c, 256-query tile). All-coalesced. ------
// Stage channel row (32 KB) + idx tile (16 KB) in LDS; thread = one query;
// random access hits LDS only; output = 128 B contiguous per thread.
__global__ __launch_bounds__(256) void k_gather(
    const u16* __restrict__ idx,        // (B,M,32)
    const float* __restrict__ xt,       // (B,3,N)
    const float* __restrict__ feat,     // (B,C,N)
    const float* __restrict__ new_xyz,  // (B,M,3)
    float* __restrict__ out)            // (B,67,M,32)
{
    __shared__ __align__(16) float chan[NN];    // 32 KB source channel
    __shared__ uint4 idxs4[1024];               // 16 KB idx tile (256 x 32 u16)

    const int blk = (int)blockIdx.x;
    const int b = blk / (CH * 16);
    const int rem = blk - b * (CH * 16);
    const int c = rem >> 4;
    const int m0 = (rem & 15) << 8;             // tile of 256 queries
    const int tid = (int)threadIdx.x;

    // stage source channel (coalesced float4)
    const float* src = (c < 3)
        ? xt   + ((size_t)b * 3  + c)       * NN
        : feat + ((size_t)b * CC + (c - 3)) * NN;
    const float4* s4 = (const float4*)src;
    float4* c4 = (float4*)chan;
    #pragma unroll
    for (int k = 0; k < 8; ++k) c4[(k << 8) + tid] = s4[(k << 8) + tid];

    // stage idx tile (contiguous 16 KB, coalesced uint4)
    const uint4* i4 = (const uint4*)(idx + ((size_t)b * MM + m0) * SS);
    #pragma unroll
    for (int k = 0; k < 4; ++k) idxs4[(k << 8) + tid] = i4[(k << 8) + tid];

    // per-query center component (0 for feature channels)
    float cw = 0.0f;
    if (c < 3) cw = new_xyz[((size_t)b * MM + m0 + tid) * 3 + c];
    __syncthreads();

    const u16* myidx = (const u16*)idxs4 + tid * SS;
    float* orow = out + (((size_t)b * CH + c) * MM + (m0 + tid)) * SS;

    #pragma unroll
    for (int j = 0; j < 8; ++j) {
        f32x4 v;
        v.x = __fsub_rn(chan[myidx[(j << 2) + 0]], cw);
        v.y = __fsub_rn(chan[myidx[(j << 2) + 1]], cw);
        v.z = __fsub_rn(chan[myidx[(j << 2) + 2]], cw);
        v.w = __fsub_rn(chan[myidx[(j << 2) + 3]], cw);
        __builtin_nontemporal_store(v, (f32x4*)&orow[j << 2]);
    }
}

// ---- fallback: R2-verified full-scan AoS kernel (no workspace needed) ------
__global__ __launch_bounds__(256) void qg_fused_kernel(
    const float* __restrict__ xyz, const float* __restrict__ new_xyz,
    const float* __restrict__ feat, float* __restrict__ out)
{
    const int wave = (int)((blockIdx.x * blockDim.x + threadIdx.x) >> 6);
    const int lane = (int)(threadIdx.x & 63);
    const int b = wave / MM;
    const int m = wave % MM;

    const float* __restrict__ xb = xyz + (size_t)b * NN * 3;
    const size_t qoff = ((size_t)b * MM + m) * 3;
    const float cx = new_xyz[qoff + 0];
    const float cy = new_xyz[qoff + 1];
    const float cz = new_xyz[qoff + 2];
    const float rr = kRR;

    int my_nb = -1;
    int cnt = 0;

    for (int base = 0; base < NN; base += 512) {
        float px[8], py[8], pz[8];
        #pragma unroll
        for (int k = 0; k < 8; ++k) {
            const int i = base + (k << 6) + lane;
            px[k] = xb[i * 3 + 0]; py[k] = xb[i * 3 + 1]; pz[k] = xb[i * 3 + 2];
        }
        #pragma unroll
        for (int k = 0; k < 8; ++k) {
            const float dx = __fsub_rn(px[k], cx);
            const float dy = __fsub_rn(py[k], cy);
            const float dz = __fsub_rn(pz[k], cz);
            const float d2 = __fadd_rn(__fadd_rn(__fmul_rn(dx, dx), __fmul_rn(dy, dy)),
                                       __fmul_rn(dz, dz));
            const bool hit = d2 < rr;
            const unsigned long long mask = __ballot(hit);
            const int pc = __popcll(mask);
            if (pc) {
                const int rank = cnt + (int)__popcll(mask & ((1ull << lane) - 1ull));
                const int addr = (hit && rank < 63) ? rank : 63;
                const int recv = __builtin_amdgcn_ds_permute(addr << 2,
                                                             base + (k << 6) + lane);
                if (lane >= cnt && lane < SS && (lane - cnt) < pc) my_nb = recv;
                cnt += pc;
                if (cnt >= SS) break;
            }
        }
        if (cnt >= SS) break;
    }

    int first = __shfl(my_nb, 0);
    if (first < 0) first = 0;
    if (lane < SS && my_nb < 0) my_nb = first;
    const int n_of = __shfl(my_nb, lane & 31);

    const int s = lane & 31;
    const int h = lane >> 5;
    const size_t obase = ((size_t)b * CH) * (size_t)(MM * SS) + (size_t)m * SS + s;
    const float* __restrict__ fb = feat + (size_t)b * CC * NN;
    #pragma unroll 2
    for (int cc = 0; cc < CH + 1; cc += 2) {
        const int c = cc + h;
        if (c < CH) {
            float v;
            if (c < 3) {
                const float center = (c == 0) ? cx : (c == 1) ? cy : cz;
                v = __fsub_rn(xb[(size_t)n_of * 3 + c], center);
            } else {
                v = fb[(size_t)(c - 3) * NN + n_of];
            }
            out[obase + (size_t)c * (size_t)(MM * SS)] = v;
        }
    }
}

extern "C" void kernel_launch(void* const* d_in, const int* in_sizes, int n_in,
                              void* d_out, int out_size, void* d_ws, size_t ws_size,
                              hipStream_t stream) {
    const float* xyz     = (const float*)d_in[0];  // (4,8192,3)
    const float* new_xyz = (const float*)d_in[1];  // (4,4096,3)
    const float* feat    = (const float*)d_in[2];  // (4,64,8192)
    float* out = (float*)d_out;                    // (4,67,4096,32)

    // ws layout: pk (512 KB, 16B-aligned) | xt (384 KB) | cellStart | idx (1 MB)
    char* base = (char*)(((uintptr_t)d_ws + 15) & ~(uintptr_t)15);
    float4* pk     = (float4*)base;
    float*  xt     = (float*)(base + (size_t)BB * NN * sizeof(float4));
    int*    cellSt = (int*)((char*)xt + (size_t)BB * 3 * NN * sizeof(float));
    u16*    idxp   = (u16*)(cellSt + BB * (NC + 1));
    const size_t need = ((char*)(idxp + (size_t)BB * MM * SS) - (char*)d_ws);

    if (ws_size >= need) {
        k_prep <<<BB, 1024, 0, stream>>>(xyz, xt, cellSt, pk);
        k_ballq<<<(BB * MM) / 8, 256, 0, stream>>>(pk, cellSt, new_xyz, idxp);
        k_gather<<<BB * CH * 16, 256, 0, stream>>>(idxp, xt, feat, new_xyz, out);
    } else {
        qg_fused_kernel<<<(BB * MM) / 4, 256, 0, stream>>>(xyz, new_xyz, feat, out);
    }
}

// Round 17
// 59.545 us; speedup vs baseline: 6.1086x; 6.1086x over previous
//
#include <hip/hip_runtime.h>
#include <cstdint>
#include <cstddef>

// Problem constants (fixed by setup_inputs)
#define BB 4
#define NN 8192
#define MM 4096
#define CC 64
#define SS 32
#define CH 67      // 3 (xyz) + 64 (features)
#define NC 512     // 8x8x8 grid cells per batch
#define QT 128     // queries per gather tile
#define RMARG 0.1201f   // conservative cell-range radius (> sqrt(kRR) + fp slop)

typedef float f32x4 __attribute__((ext_vector_type(4)));   // nt-store-able 16B
typedef unsigned short u16;

// radius^2 exactly as Python computes it: double 0.12*0.12 rounded once to f32.
__device__ __constant__ float kRR = (float)(0.12 * 0.12);

__device__ __forceinline__ int cell_of(float x, float y, float z) {
    const int ix = min((int)(x * 8.0f), 7);
    const int iy = min((int)(y * 8.0f), 7);
    const int iz = min((int)(z * 8.0f), 7);
    return (ix << 6) + (iy << 3) + iz;   // z contiguous within (ix,iy) row
}

// inclusive scan over 512 values (tid 0..511, 8 waves); wsum = LDS int[16].
__device__ __forceinline__ int block_scan512(int v, int tid, int* wsum) {
    int incl = v;
    #pragma unroll
    for (int d = 1; d < 64; d <<= 1) {
        const int t = __shfl_up(incl, d);
        if ((tid & 63) >= d) incl += t;
    }
    if ((tid & 63) == 63 && tid < NC) wsum[tid >> 6] = incl;
    __syncthreads();
    if (tid < 8) {
        const int ws = wsum[tid];
        int w2 = ws;
        #pragma unroll
        for (int d = 1; d < 8; d <<= 1) {
            const int t = __shfl_up(w2, d);
            if (tid >= d) w2 += t;
        }
        wsum[tid] = w2 - ws;   // exclusive wave-offset
    }
    __syncthreads();
    return incl + wsum[(tid >> 6) & 7];
}

// ---- k_prep: grid build + xyz SoA, 4 blocks x 1024 (verified R16) ----------
__global__ __launch_bounds__(1024) void k_prep(
    const float* __restrict__ xyz,      // (B,N,3)
    float* __restrict__ xt,             // (B,3,N) out plain SoA
    int* __restrict__ cellStart,        // (B,513) out
    float4* __restrict__ pk)            // (B,N) out packed cell-ordered
{
    __shared__ int sm[NC];
    __shared__ int cur[NC];
    __shared__ int wsum[16];
    const int b = (int)blockIdx.x;
    const int tid = (int)threadIdx.x;

    if (tid < NC) sm[tid] = 0;
    __syncthreads();

    float xs[8], ys[8], zs[8];
    int cl[8];
    const float* __restrict__ xb = xyz + (size_t)b * NN * 3;
    float* __restrict__ xtb = xt + (size_t)b * 3 * NN;
    #pragma unroll
    for (int k = 0; k < 8; ++k) {
        const int n = (k << 10) + tid;
        xs[k] = xb[n * 3 + 0];
        ys[k] = xb[n * 3 + 1];
        zs[k] = xb[n * 3 + 2];
        cl[k] = cell_of(xs[k], ys[k], zs[k]);
        atomicAdd(&sm[cl[k]], 1);
        xtb[0 * NN + n] = xs[k];        // coalesced SoA writes
        xtb[1 * NN + n] = ys[k];
        xtb[2 * NN + n] = zs[k];
    }
    __syncthreads();

    const int v = (tid < NC) ? sm[tid] : 0;
    const int incl = block_scan512(v, tid, wsum);
    if (tid < NC) {
        cellStart[b * (NC + 1) + tid + 1] = incl;
        cur[tid] = incl - v;                   // exclusive prefix
        if (tid == 0) cellStart[b * (NC + 1)] = 0;
    }
    __syncthreads();

    #pragma unroll
    for (int k = 0; k < 8; ++k) {
        const int n = (k << 10) + tid;
        const int pos = atomicAdd(&cur[cl[k]], 1);
        pk[b * NN + pos] = make_float4(xs[k], ys[k], zs[k], __int_as_float(n));
    }
}

// ---- k_ballq: bitmap ball-query (verified R12/R16); writes u16 idx ---------
__global__ __launch_bounds__(256) void k_ballq(
    const float4* __restrict__ pk,      // (B,N) packed cell-ordered (x,y,z,idx)
    const int* __restrict__ cellStart,  // (B,513)
    const float* __restrict__ new_xyz,  // (B,M,3)
    u16* __restrict__ idx)              // (B,M,32) out
{
    __shared__ unsigned int bm[4][2][NN / 32];   // 1 KiB bitmap per query
    __shared__ int slots_sm[4][2][SS];

    const int tid = (int)threadIdx.x;
    const int lane = tid & 63;
    const int w = tid >> 6;
    const int pair = (int)blockIdx.x * 4 + w;    // 0 .. BB*MM/2-1
    const int b = pair >> 11;                    // / (MM/2)
    const int m0 = (pair & 2047) << 1;           // even query index

    #pragma unroll
    for (int k = 0; k < 8; ++k) bm[w][k & 1][((k >> 1) << 6) + lane] = 0u;

    const float* __restrict__ qb = new_xyz + ((size_t)b * MM + m0) * 3;
    const float cxq[2] = { qb[0], qb[3] };
    const float cyq[2] = { qb[1], qb[4] };
    const float czq[2] = { qb[2], qb[5] };
    const float rr = kRR;

    const int* __restrict__ cs = cellStart + b * (NC + 1);
    const float4* __restrict__ pb = pk + b * NN;

    int Kcq[2];

    #pragma unroll
    for (int q = 0; q < 2; ++q) {               // compile-time unrolled
        const float cx = cxq[q], cy = cyq[q], cz = czq[q];
        unsigned int* __restrict__ bitmap = bm[w][q];
        int* __restrict__ slot = slots_sm[w][q];

        const int x0 = max(0, (int)((cx - RMARG) * 8.0f));
        const int x1 = min(7, (int)((cx + RMARG) * 8.0f));
        const int y0 = max(0, (int)((cy - RMARG) * 8.0f));
        const int y1 = min(7, (int)((cy + RMARG) * 8.0f));
        const int z0 = max(0, (int)((cz - RMARG) * 8.0f));
        const int z1 = min(7, (int)((cz + RMARG) * 8.0f));

        // prefetch all pair bounds lane-parallel (npair <= 9)
        const int ny = y1 - y0 + 1;
        const int npair = (x1 - x0 + 1) * ny;
        int begL = 0, endL = 0;
        if (lane < npair) {
            const int px = lane / ny;
            const int py = lane - px * ny;
            const int cb2 = ((x0 + px) << 6) + ((y0 + py) << 3);
            begL = cs[cb2 + z0];
            endL = cs[cb2 + z1 + 1];
        }

        for (int p = 0; p < npair; ++p) {
            const int beg = __shfl(begL, p);
            const int end = __shfl(endL, p);
            for (int off = beg; off < end; off += 64) {
                const int a = off + lane;
                const bool act = a < end;
                const float4 v = pb[act ? a : beg];   // coalesced 16B/lane
                const float dx = __fsub_rn(v.x, cx);
                const float dy = __fsub_rn(v.y, cy);
                const float dz = __fsub_rn(v.z, cz);
                const float d2 = __fadd_rn(__fadd_rn(__fmul_rn(dx, dx), __fmul_rn(dy, dy)),
                                           __fmul_rn(dz, dz));
                if (act && d2 < rr) {
                    const int n = __float_as_int(v.w);
                    atomicOr(&bitmap[n >> 5], 1u << (n & 31));
                }
            }
        }

        // extract first SS set bits, ascending (verified R9..R16)
        const uint4 wv = *reinterpret_cast<const uint4*>(&bitmap[lane << 2]);
        const int pc = __popc(wv.x) + __popc(wv.y) + __popc(wv.z) + __popc(wv.w);
        int incl = pc;
        #pragma unroll
        for (int d = 1; d < 64; d <<= 1) {
            const int t = __shfl_up(incl, d);
            if (lane >= d) incl += t;
        }
        const int K = __shfl(incl, 63);
        int r = incl - pc;
        if (r < SS) {
            const int base = lane << 7;
            unsigned int mw0 = wv.x, mw1 = wv.y, mw2 = wv.z, mw3 = wv.w;
            while (mw0 && r < SS) { slot[r++] = base +  0 + __builtin_ctz(mw0); mw0 &= mw0 - 1; }
            while (mw1 && r < SS) { slot[r++] = base + 32 + __builtin_ctz(mw1); mw1 &= mw1 - 1; }
            while (mw2 && r < SS) { slot[r++] = base + 64 + __builtin_ctz(mw2); mw2 &= mw2 - 1; }
            while (mw3 && r < SS) { slot[r++] = base + 96 + __builtin_ctz(mw3); mw3 &= mw3 - 1; }
        }
        Kcq[q] = (K < SS) ? K : SS;
    }
    // same-wave LDS write->read is in-order; no barrier needed.

    const int q = lane >> 5;
    const int s = lane & 31;
    const int Kc = q ? Kcq[1] : Kcq[0];
    int n_of;
    if (Kc == 0) n_of = 0;                      // no hits: reference yields idx 0
    else n_of = slots_sm[w][q][(s < Kc) ? s : 0];

    // wave writes 64 u16 = 128 B contiguous (slots of m0 then m0+1)
    u16* dst = idx + ((size_t)b * MM + m0) * SS;
    dst[lane] = (u16)n_of;
}

// ---- k_gather: block = (b, channel c, 128-query tile). --------------------
// Channel row staged in LDS (coalesced); idx read as coalesced ushort4
// (8 consecutive threads cover one query row); every nt store instruction
// = 64 lanes x 16 B CONSECUTIVE = 1 KB contiguous (R16's stride bug fixed).
__global__ __launch_bounds__(256) void k_gather(
    const u16* __restrict__ idx,        // (B,M,32)
    const float* __restrict__ xt,       // (B,3,N)
    const float* __restrict__ feat,     // (B,C,N)
    const float* __restrict__ new_xyz,  // (B,M,3)
    float* __restrict__ out)            // (B,67,M,32)
{
    __shared__ __align__(16) float chan[NN];    // 32 KB source channel
    __shared__ float cq[QT];                    // per-query center component

    const int blk = (int)blockIdx.x;
    const int ntile = MM / QT;                  // 32
    const int b = blk / (CH * ntile);
    const int rem = blk - b * (CH * ntile);
    const int c = rem / ntile;
    const int m0 = (rem - c * ntile) * QT;
    const int tid = (int)threadIdx.x;

    // stage source channel (coalesced float4, 8 per thread)
    const float* src = (c < 3)
        ? xt   + ((size_t)b * 3  + c)       * NN
        : feat + ((size_t)b * CC + (c - 3)) * NN;
    const float4* s4 = (const float4*)src;
    float4* c4 = (float4*)chan;
    #pragma unroll
    for (int k = 0; k < 8; ++k) c4[(k << 8) + tid] = s4[(k << 8) + tid];

    if (tid < QT)
        cq[tid] = (c < 3) ? new_xyz[((size_t)b * MM + m0 + tid) * 3 + c] : 0.0f;
    __syncthreads();

    const u16* ip = idx + ((size_t)b * MM + m0) * SS;
    float* obase = out + (((size_t)b * CH + c) * MM + m0) * SS;

    #pragma unroll
    for (int k = 0; k < 4; ++k) {
        const int p = (k << 8) + tid;           // f32x4 position (0..1023)
        const int qq = p >> 3;                  // query within tile
        const int s0 = (p & 7) << 2;            // first slot of this f32x4
        const ushort4 id = *(const ushort4*)&ip[qq * SS + s0];  // 8B coalesced
        const float w = cq[qq];
        f32x4 v;
        v.x = __fsub_rn(chan[id.x], w);
        v.y = __fsub_rn(chan[id.y], w);
        v.z = __fsub_rn(chan[id.z], w);
        v.w = __fsub_rn(chan[id.w], w);
        __builtin_nontemporal_store(v, (f32x4*)&obase[p << 2]);  // 1KB/instr
    }
}

// ---- fallback: R2-verified full-scan AoS kernel (no workspace needed) ------
__global__ __launch_bounds__(256) void qg_fused_kernel(
    const float* __restrict__ xyz, const float* __restrict__ new_xyz,
    const float* __restrict__ feat, float* __restrict__ out)
{
    const int wave = (int)((blockIdx.x * blockDim.x + threadIdx.x) >> 6);
    const int lane = (int)(threadIdx.x & 63);
    const int b = wave / MM;
    const int m = wave % MM;

    const float* __restrict__ xb = xyz + (size_t)b * NN * 3;
    const size_t qoff = ((size_t)b * MM + m) * 3;
    const float cx = new_xyz[qoff + 0];
    const float cy = new_xyz[qoff + 1];
    const float cz = new_xyz[qoff + 2];
    const float rr = kRR;

    int my_nb = -1;
    int cnt = 0;

    for (int base = 0; base < NN; base += 512) {
        float px[8], py[8], pz[8];
        #pragma unroll
        for (int k = 0; k < 8; ++k) {
            const int i = base + (k << 6) + lane;
            px[k] = xb[i * 3 + 0]; py[k] = xb[i * 3 + 1]; pz[k] = xb[i * 3 + 2];
        }
        #pragma unroll
        for (int k = 0; k < 8; ++k) {
            const float dx = __fsub_rn(px[k], cx);
            const float dy = __fsub_rn(py[k], cy);
            const float dz = __fsub_rn(pz[k], cz);
            const float d2 = __fadd_rn(__fadd_rn(__fmul_rn(dx, dx), __fmul_rn(dy, dy)),
                                       __fmul_rn(dz, dz));
            const bool hit = d2 < rr;
            const unsigned long long mask = __ballot(hit);
            const int pc = __popcll(mask);
            if (pc) {
                const int rank = cnt + (int)__popcll(mask & ((1ull << lane) - 1ull));
                const int addr = (hit && rank < 63) ? rank : 63;
                const int recv = __builtin_amdgcn_ds_permute(addr << 2,
                                                             base + (k << 6) + lane);
                if (lane >= cnt && lane < SS && (lane - cnt) < pc) my_nb = recv;
                cnt += pc;
                if (cnt >= SS) break;
            }
        }
        if (cnt >= SS) break;
    }

    int first = __shfl(my_nb, 0);
    if (first < 0) first = 0;
    if (lane < SS && my_nb < 0) my_nb = first;
    const int n_of = __shfl(my_nb, lane & 31);

    const int s = lane & 31;
    const int h = lane >> 5;
    const size_t obase = ((size_t)b * CH) * (size_t)(MM * SS) + (size_t)m * SS + s;
    const float* __restrict__ fb = feat + (size_t)b * CC * NN;
    #pragma unroll 2
    for (int cc = 0; cc < CH + 1; cc += 2) {
        const int c = cc + h;
        if (c < CH) {
            float v;
            if (c < 3) {
                const float center = (c == 0) ? cx : (c == 1) ? cy : cz;
                v = __fsub_rn(xb[(size_t)n_of * 3 + c], center);
            } else {
                v = fb[(size_t)(c - 3) * NN + n_of];
            }
            out[obase + (size_t)c * (size_t)(MM * SS)] = v;
        }
    }
}

extern "C" void kernel_launch(void* const* d_in, const int* in_sizes, int n_in,
                              void* d_out, int out_size, void* d_ws, size_t ws_size,
                              hipStream_t stream) {
    const float* xyz     = (const float*)d_in[0];  // (4,8192,3)
    const float* new_xyz = (const float*)d_in[1];  // (4,4096,3)
    const float* feat    = (const float*)d_in[2];  // (4,64,8192)
    float* out = (float*)d_out;                    // (4,67,4096,32)

    // ws layout: pk (512 KB, 16B-aligned) | xt (384 KB) | cellStart | idx (1 MB)
    char* base = (char*)(((uintptr_t)d_ws + 15) & ~(uintptr_t)15);
    float4* pk     = (float4*)base;
    float*  xt     = (float*)(base + (size_t)BB * NN * sizeof(float4));
    int*    cellSt = (int*)((char*)xt + (size_t)BB * 3 * NN * sizeof(float));
    u16*    idxp   = (u16*)(cellSt + BB * (NC + 1));
    const size_t need = ((char*)(idxp + (size_t)BB * MM * SS) - (char*)d_ws);

    if (ws_size >= need) {
        k_prep <<<BB, 1024, 0, stream>>>(xyz, xt, cellSt, pk);
        k_ballq<<<(BB * MM) / 8, 256, 0, stream>>>(pk, cellSt, new_xyz, idxp);
        k_gather<<<BB * CH * (MM / QT), 256, 0, stream>>>(idxp, xt, feat, new_xyz, out);
    } else {
        qg_fused_kernel<<<(BB * MM) / 4, 256, 0, stream>>>(xyz, new_xyz, feat, out);
    }
}

// Round 18
// 57.042 us; speedup vs baseline: 6.3766x; 1.0439x over previous
//
#include <hip/hip_runtime.h>
#include <cstdint>
#include <cstddef>

// Problem constants (fixed by setup_inputs)
#define BB 4
#define NN 8192
#define MM 4096
#define CC 64
#define SS 32
#define CH 67      // 3 (xyz) + 64 (features)
#define NC 512     // 8x8x8 grid cells per batch
#define RMARG 0.1201f   // conservative cell-range radius (> sqrt(kRR) + fp slop)

// radius^2 exactly as Python computes it: double 0.12*0.12 rounded once to f32.
__device__ __constant__ float kRR = (float)(0.12 * 0.12);

__device__ __forceinline__ int cell_of(float x, float y, float z) {
    const int ix = min((int)(x * 8.0f), 7);
    const int iy = min((int)(y * 8.0f), 7);
    const int iz = min((int)(z * 8.0f), 7);
    return (ix << 6) + (iy << 3) + iz;   // z contiguous within (ix,iy) row
}

// inclusive scan over 512 values (tid 0..511, 8 waves); wsum = LDS int[16].
__device__ __forceinline__ int block_scan512(int v, int tid, int* wsum) {
    int incl = v;
    #pragma unroll
    for (int d = 1; d < 64; d <<= 1) {
        const int t = __shfl_up(incl, d);
        if ((tid & 63) >= d) incl += t;
    }
    if ((tid & 63) == 63 && tid < NC) wsum[tid >> 6] = incl;
    __syncthreads();
    if (tid < 8) {
        const int ws = wsum[tid];
        int w2 = ws;
        #pragma unroll
        for (int d = 1; d < 8; d <<= 1) {
            const int t = __shfl_up(w2, d);
            if (tid >= d) w2 += t;
        }
        wsum[tid] = w2 - ws;   // exclusive wave-offset
    }
    __syncthreads();
    return incl + wsum[(tid >> 6) & 7];
}

// ---- k_prep: grid build + query sort (blocks 0..3) + feat transpose --------
__global__ __launch_bounds__(1024) void k_prep(
    const float* __restrict__ xyz,      // (B,N,3)
    const float* __restrict__ new_xyz,  // (B,M,3)
    const float* __restrict__ feat,     // (B,C,N)
    float* __restrict__ ft,             // (B,N,C) out
    int* __restrict__ cellStart,        // (B,513) out
    int* __restrict__ qperm,            // (B,M) out: sorted-order -> orig m
    float4* __restrict__ pk)            // (B,N) out packed cell-ordered
{
    __shared__ __align__(16) char smem[64 * 65 * sizeof(float)];  // union
    const int blk = (int)blockIdx.x;
    const int tid = (int)threadIdx.x;

    if (blk < BB) {
        int* sm   = (int*)smem;        // [NC] counts
        int* cur  = sm + NC;           // [NC] scatter cursors
        int* wsum = cur + NC;          // [16] scan partials
        const int b = blk;

        if (tid < NC) sm[tid] = 0;
        __syncthreads();

        float xs[8], ys[8], zs[8];
        int cl[8];
        const float* __restrict__ xb = xyz + (size_t)b * NN * 3;
        #pragma unroll
        for (int k = 0; k < 8; ++k) {
            const int n = (k << 10) + tid;
            xs[k] = xb[n * 3 + 0];
            ys[k] = xb[n * 3 + 1];
            zs[k] = xb[n * 3 + 2];
            cl[k] = cell_of(xs[k], ys[k], zs[k]);
            atomicAdd(&sm[cl[k]], 1);
        }
        __syncthreads();

        const int v = (tid < NC) ? sm[tid] : 0;
        const int incl = block_scan512(v, tid, wsum);
        if (tid < NC) {
            cellStart[b * (NC + 1) + tid + 1] = incl;
            cur[tid] = incl - v;                   // exclusive prefix
            if (tid == 0) cellStart[b * (NC + 1)] = 0;
        }
        __syncthreads();

        #pragma unroll
        for (int k = 0; k < 8; ++k) {
            const int n = (k << 10) + tid;
            const int pos = atomicAdd(&cur[cl[k]], 1);
            pk[b * NN + pos] = make_float4(xs[k], ys[k], zs[k], __int_as_float(n));
        }
        __syncthreads();

        // ---------------- query sort by cell (M=4096) ----------------
        if (tid < NC) sm[tid] = 0;
        __syncthreads();
        int qcl[4];
        const float* __restrict__ qb = new_xyz + (size_t)b * MM * 3;
        #pragma unroll
        for (int k = 0; k < 4; ++k) {
            const int qm = (k << 10) + tid;
            const float qx = qb[qm * 3 + 0];
            const float qy = qb[qm * 3 + 1];
            const float qz = qb[qm * 3 + 2];
            qcl[k] = cell_of(qx, qy, qz);
            atomicAdd(&sm[qcl[k]], 1);
        }
        __syncthreads();
        const int qv = (tid < NC) ? sm[tid] : 0;
        const int qincl = block_scan512(qv, tid, wsum);
        if (tid < NC) cur[tid] = qincl - qv;
        __syncthreads();
        #pragma unroll
        for (int k = 0; k < 4; ++k) {
            const int qm = (k << 10) + tid;
            const int pos = atomicAdd(&cur[qcl[k]], 1);
            qperm[b * MM + pos] = qm;
        }
    } else {
        // ---------------- feat (B,C,N) -> ft (B,N,C) tile transpose ---------
        float (*tile)[65] = (float(*)[65])smem;
        const int blk2 = blk - BB;
        const int b = blk2 / (NN / 64);
        const int n0 = (blk2 % (NN / 64)) * 64;
        const int tn = tid & 63;
        const int q = tid >> 6;                   // 0..15
        const float* __restrict__ fb = feat + (size_t)b * CC * NN;
        #pragma unroll
        for (int k = 0; k < 4; ++k) {
            const int c = (q << 2) + k;
            tile[tn][c] = fb[(size_t)c * NN + n0 + tn];   // coalesced along N
        }
        __syncthreads();
        float* fo = ft + ((size_t)b * NN + n0) * CC;
        #pragma unroll
        for (int k = 0; k < 4; ++k) {
            const int rn = (q << 2) + k;
            fo[(size_t)rn * CC + tn] = tile[rn][tn];      // coalesced along C
        }
    }
}

// ---- main: grid ball-query via per-wave LDS BITMAP + group -----------------
// out is write-once streaming: non-temporal stores bypass L2 write-allocate,
// keeping pk/cellStart/ft resident.
__global__ __launch_bounds__(256) void qg_grid_kernel(
    const float4* __restrict__ pk,      // (B,N) packed cell-ordered (x,y,z,idx)
    const int* __restrict__ cellStart,  // (B,513)
    const int* __restrict__ qperm,      // (B,M)
    const float* __restrict__ ft,       // (B,N,C) transposed feat
    const float* __restrict__ xyz,      // (B,N,3)
    const float* __restrict__ new_xyz,  // (B,M,3)
    float* __restrict__ out)            // (B,67,M,32)
{
    __shared__ unsigned int bm[4][NN / 32];   // 1 KiB bitmap per wave
    __shared__ int slots_sm[4][SS];

    const int tid = (int)threadIdx.x;
    const int lane = tid & 63;
    const int w = tid >> 6;
    const int wave = (int)blockIdx.x * 4 + w;
    const int b = wave >> 12;           // / MM
    const int msort = wave & (MM - 1);
    const int m = qperm[b * MM + msort];   // original query index

    unsigned int* __restrict__ bitmap = bm[w];
    int* __restrict__ slot = slots_sm[w];

    #pragma unroll
    for (int k = 0; k < 4; ++k) bitmap[(k << 6) + lane] = 0u;

    const float* __restrict__ xb = xyz + (size_t)b * NN * 3;
    const size_t qoff = ((size_t)b * MM + m) * 3;
    const float cx = new_xyz[qoff + 0];
    const float cy = new_xyz[qoff + 1];
    const float cz = new_xyz[qoff + 2];
    const float rr = kRR;

    const int x0 = max(0, (int)((cx - RMARG) * 8.0f));
    const int x1 = min(7, (int)((cx + RMARG) * 8.0f));
    const int y0 = max(0, (int)((cy - RMARG) * 8.0f));
    const int y1 = min(7, (int)((cy + RMARG) * 8.0f));
    const int z0 = max(0, (int)((cz - RMARG) * 8.0f));
    const int z1 = min(7, (int)((cz + RMARG) * 8.0f));

    const int* __restrict__ cs = cellStart + b * (NC + 1);
    const float4* __restrict__ pb = pk + b * NN;

    // prefetch all pair bounds lane-parallel (npair <= 9)
    const int ny = y1 - y0 + 1;
    const int npair = (x1 - x0 + 1) * ny;
    int begL = 0, endL = 0;
    if (lane < npair) {
        const int px = lane / ny;
        const int py = lane - px * ny;
        const int cb2 = ((x0 + px) << 6) + ((y0 + py) << 3);
        begL = cs[cb2 + z0];
        endL = cs[cb2 + z1 + 1];
    }

    for (int p = 0; p < npair; ++p) {
        const int beg = __shfl(begL, p);
        const int end = __shfl(endL, p);
        for (int off = beg; off < end; off += 64) {
            const int a = off + lane;
            const bool act = a < end;
            const float4 v = pb[act ? a : beg];   // coalesced 16B/lane
            const float dx = __fsub_rn(v.x, cx);
            const float dy = __fsub_rn(v.y, cy);
            const float dz = __fsub_rn(v.z, cz);
            const float d2 = __fadd_rn(__fadd_rn(__fmul_rn(dx, dx), __fmul_rn(dy, dy)),
                                       __fmul_rn(dz, dz));
            if (act && d2 < rr) {
                const int n = __float_as_int(v.w);
                atomicOr(&bitmap[n >> 5], 1u << (n & 31));
            }
        }
    }

    // ---- extract first SS set bits, ascending (verified R9..R12) ----
    const uint4 wv = *reinterpret_cast<const uint4*>(&bitmap[lane << 2]);
    const int pc = __popc(wv.x) + __popc(wv.y) + __popc(wv.z) + __popc(wv.w);
    int incl = pc;
    #pragma unroll
    for (int d = 1; d < 64; d <<= 1) {
        const int t = __shfl_up(incl, d);
        if (lane >= d) incl += t;
    }
    const int K = __shfl(incl, 63);     // total hits (uniform)
    int r = incl - pc;                  // exclusive prefix: my first rank
    if (r < SS) {
        const int base = lane << 7;     // lane*128 bits
        unsigned int mw0 = wv.x, mw1 = wv.y, mw2 = wv.z, mw3 = wv.w;
        while (mw0 && r < SS) { slot[r++] = base +  0 + __builtin_ctz(mw0); mw0 &= mw0 - 1; }
        while (mw1 && r < SS) { slot[r++] = base + 32 + __builtin_ctz(mw1); mw1 &= mw1 - 1; }
        while (mw2 && r < SS) { slot[r++] = base + 64 + __builtin_ctz(mw2); mw2 &= mw2 - 1; }
        while (mw3 && r < SS) { slot[r++] = base + 96 + __builtin_ctz(mw3); mw3 &= mw3 - 1; }
    }
    // same-wave LDS write->read is in-order; no barrier needed.

    const int s = lane & 31;
    const int h = lane >> 5;
    const int Kc = (K < SS) ? K : SS;
    int n_of;
    if (Kc == 0) n_of = 0;                       // no hits: reference yields idx 0
    else n_of = (s < Kc) ? slot[s] : slot[0];    // pad with first (smallest) index

    const size_t obase = ((size_t)b * CH) * (size_t)(MM * SS) + (size_t)m * SS + s;

    if (h == 0) {
        const float* xr = xb + (size_t)n_of * 3;
        __builtin_nontemporal_store(__fsub_rn(xr[0], cx), &out[obase + 0 * (size_t)(MM * SS)]);
        __builtin_nontemporal_store(__fsub_rn(xr[1], cy), &out[obase + 1 * (size_t)(MM * SS)]);
        __builtin_nontemporal_store(__fsub_rn(xr[2], cz), &out[obase + 2 * (size_t)(MM * SS)]);
    }
    const float4* fr4 = (const float4*)(ft + ((size_t)b * NN + n_of) * CC + (h << 5));
    float4 f[8];
    #pragma unroll
    for (int j = 0; j < 8; ++j) f[j] = fr4[j];
    #pragma unroll
    for (int j = 0; j < 8; ++j) {
        float* cb = &out[obase + (size_t)(3 + (h << 5) + (j << 2)) * (size_t)(MM * SS)];
        __builtin_nontemporal_store(f[j].x, cb + 0 * (size_t)(MM * SS));
        __builtin_nontemporal_store(f[j].y, cb + 1 * (size_t)(MM * SS));
        __builtin_nontemporal_store(f[j].z, cb + 2 * (size_t)(MM * SS));
        __builtin_nontemporal_store(f[j].w, cb + 3 * (size_t)(MM * SS));
    }
}

// ---- fallback: R2-verified full-scan AoS kernel (no workspace needed) ------
__global__ __launch_bounds__(256) void qg_fused_kernel(
    const float* __restrict__ xyz, const float* __restrict__ new_xyz,
    const float* __restrict__ feat, float* __restrict__ out)
{
    const int wave = (int)((blockIdx.x * blockDim.x + threadIdx.x) >> 6);
    const int lane = (int)(threadIdx.x & 63);
    const int b = wave / MM;
    const int m = wave % MM;

    const float* __restrict__ xb = xyz + (size_t)b * NN * 3;
    const size_t qoff = ((size_t)b * MM + m) * 3;
    const float cx = new_xyz[qoff + 0];
    const float cy = new_xyz[qoff + 1];
    const float cz = new_xyz[qoff + 2];
    const float rr = kRR;

    int my_nb = -1;
    int cnt = 0;

    for (int base = 0; base < NN; base += 512) {
        float px[8], py[8], pz[8];
        #pragma unroll
        for (int k = 0; k < 8; ++k) {
            const int i = base + (k << 6) + lane;
            px[k] = xb[i * 3 + 0]; py[k] = xb[i * 3 + 1]; pz[k] = xb[i * 3 + 2];
        }
        #pragma unroll
        for (int k = 0; k < 8; ++k) {
            const float dx = __fsub_rn(px[k], cx);
            const float dy = __fsub_rn(py[k], cy);
            const float dz = __fsub_rn(pz[k], cz);
            const float d2 = __fadd_rn(__fadd_rn(__fmul_rn(dx, dx), __fmul_rn(dy, dy)),
                                       __fmul_rn(dz, dz));
            const bool hit = d2 < rr;
            const unsigned long long mask = __ballot(hit);
            const int pc = __popcll(mask);
            if (pc) {
                const int rank = cnt + (int)__popcll(mask & ((1ull << lane) - 1ull));
                const int addr = (hit && rank < 63) ? rank : 63;
                const int recv = __builtin_amdgcn_ds_permute(addr << 2,
                                                             base + (k << 6) + lane);
                if (lane >= cnt && lane < SS && (lane - cnt) < pc) my_nb = recv;
                cnt += pc;
                if (cnt >= SS) break;
            }
        }
        if (cnt >= SS) break;
    }

    int first = __shfl(my_nb, 0);
    if (first < 0) first = 0;
    if (lane < SS && my_nb < 0) my_nb = first;
    const int n_of = __shfl(my_nb, lane & 31);

    const int s = lane & 31;
    const int h = lane >> 5;
    const size_t obase = ((size_t)b * CH) * (size_t)(MM * SS) + (size_t)m * SS + s;
    const float* __restrict__ fb = feat + (size_t)b * CC * NN;
    #pragma unroll 2
    for (int cc = 0; cc < CH + 1; cc += 2) {
        const int c = cc + h;
        if (c < CH) {
            float v;
            if (c < 3) {
                const float center = (c == 0) ? cx : (c == 1) ? cy : cz;
                v = __fsub_rn(xb[(size_t)n_of * 3 + c], center);
            } else {
                v = fb[(size_t)(c - 3) * NN + n_of];
            }
            out[obase + (size_t)c * (size_t)(MM * SS)] = v;
        }
    }
}

extern "C" void kernel_launch(void* const* d_in, const int* in_sizes, int n_in,
                              void* d_out, int out_size, void* d_ws, size_t ws_size,
                              hipStream_t stream) {
    const float* xyz     = (const float*)d_in[0];  // (4,8192,3)
    const float* new_xyz = (const float*)d_in[1];  // (4,4096,3)
    const float* feat    = (const float*)d_in[2];  // (4,64,8192)
    float* out = (float*)d_out;                    // (4,67,4096,32)

    // ws layout: ft (8 MiB) | cellStart | qperm | pk (16B-aligned)
    const size_t ft_b = (size_t)BB * NN * CC * sizeof(float);   // 8 MiB
    float*  ft     = (float*)d_ws;
    int*    cellSt = (int*)((char*)d_ws + ft_b);
    int*    qperm  = cellSt + BB * (NC + 1);
    char*   after  = (char*)(qperm + BB * MM);
    float4* pk     = (float4*)(((uintptr_t)after + 15) & ~(uintptr_t)15);
    const size_t need = ((char*)(pk + BB * NN) - (char*)d_ws);

    if (ws_size >= need) {
        k_prep<<<BB + BB * (NN / 64), 1024, 0, stream>>>(xyz, new_xyz, feat, ft,
                                                         cellSt, qperm, pk);
        qg_grid_kernel<<<(BB * MM) / 4, 256, 0, stream>>>(pk, cellSt, qperm, ft,
                                                          xyz, new_xyz, out);
    } else {
        qg_fused_kernel<<<(BB * MM) / 4, 256, 0, stream>>>(xyz, new_xyz, feat, out);
    }
}